// Round 3
// baseline (108.844 us; speedup 1.0000x reference)
//
#include <hip/hip_runtime.h>
#include <math.h>

#define BB 2
#define HH 256
#define WW 832
#define HWIMG (HH * WW)

#define TS 16              // output tile is 16x16, 1 px/thread, 256 thr/block
#define TXN (WW / TS)      // 52
#define TYN (HH / TS)      // 16
#define KCAP 160           // keepers in 36x36 are pairwise Chebyshev>=3 -> max 144

// Staged LDS regions (per block):
//   keeper region: tile + sense halo 10 -> rows/cols [i0-10, i0+25] (36x36)
//   src: keeper nbrs (di -2..0, dj -2..2) + theta ring +-2
//        -> origin (i0-12, j0-12), 40 x 40
//   dst: search px = keeper + (oy in [-3,3], ox in [-7,7]) + theta ring +-2
//        -> rows [i0-15, i0+30] (46), cols [j0-19, j0+34] -> origin
//        (i0-15, j0-20), 46 x 56
#define SRH 40
#define SRW 40
#define DRH 46
#define DRW 56

// ---------------------------------------------------------------------------
// Orientation at (i,j), GLOBAL memory, full wrap (jnp.roll) + one-sided
// border gradients. Used only for image-border pixels (rare).
// ---------------------------------------------------------------------------
__device__ inline float theta_at(const float* __restrict__ m, int i, int j) {
    int ri[5], cj[5];
#pragma unroll
    for (int t = 0; t < 5; ++t) {
        int r = i + t - 2; r = (r < 0) ? r + HH : (r >= HH ? r - HH : r);
        int c = j + t - 2; c = (c < 0) ? c + WW : (c >= WW ? c - WW : c);
        ri[t] = r * WW; cj[t] = c;
    }
    float S[5][5];
#pragma unroll
    for (int a = 0; a < 5; ++a)
#pragma unroll
        for (int c = 0; c < 5; ++c)
            S[a][c] = m[ri[a] + cj[c]];
    float ct[5], cm[5], cb[5];
#pragma unroll
    for (int c = 0; c < 5; ++c) {
        ct[c] = S[0][c] + S[1][c] + S[2][c];
        cm[c] = S[1][c] + S[2][c] + S[3][c];
        cb[c] = S[2][c] + S[3][c] + S[4][c];
    }
    float Bm = ct[1] + ct[2] + ct[3];
    float Bp = cb[1] + cb[2] + cb[3];
    float Bl = cm[0] + cm[1] + cm[2];
    float Br = cm[2] + cm[3] + cm[4];
    float Bc = cm[1] + cm[2] + cm[3];
    float gy = (i == 0) ? (Bp - Bc) : (i == HH - 1) ? (Bc - Bm) : 0.5f * (Bp - Bm);
    float gx = (j == 0) ? (Br - Bc) : (j == WW - 1) ? (Bc - Bl) : 0.5f * (Br - Bl);
    return atan2f(gy, gx);
}

// ---------------------------------------------------------------------------
// Orientation from a STAGED LDS region, interior pixels only (>=2 px from the
// image border): no wrap triggers, gradients purely central, staged values
// are exact copies -> bit-identical to theta_at.
// ---------------------------------------------------------------------------
__device__ inline float theta_lds(const float* __restrict__ m, int stride,
                                  int li, int lj) {
    const float* p = m + (li - 2) * stride + (lj - 2);
    float S[5][5];
#pragma unroll
    for (int a = 0; a < 5; ++a)
#pragma unroll
        for (int c = 0; c < 5; ++c)
            S[a][c] = p[a * stride + c];
    float ct[5], cm[5], cb[5];
#pragma unroll
    for (int c = 0; c < 5; ++c) {
        ct[c] = S[0][c] + S[1][c] + S[2][c];
        cm[c] = S[1][c] + S[2][c] + S[3][c];
        cb[c] = S[2][c] + S[3][c] + S[4][c];
    }
    float Bm = ct[1] + ct[2] + ct[3];
    float Bp = cb[1] + cb[2] + cb[3];
    float Bl = cm[0] + cm[1] + cm[2];
    float Br = cm[2] + cm[3] + cm[4];
    float gy = 0.5f * (Bp - Bm);
    float gx = 0.5f * (Br - Bl);
    return atan2f(gy, gx);
}

// ---------------------------------------------------------------------------
// Fused kernel: one block per 16x16 tile, 256 threads (4 waves), 1664 blocks
// -> ~6.5 blocks/CU resident, deep latency hiding. Branch-free staging:
// unconditional loads from clamped addresses + select-zero for OOB (matches
// the reference's zero-fill gather), all loads independent -> one HBM
// latency round. Then detection -> wave-per-keeper search -> diffusion
// entirely from LDS. One dispatch, no workspace.
// ---------------------------------------------------------------------------
__global__ __launch_bounds__(256) void fused_kernel(
        const float* __restrict__ src, const float* __restrict__ dst,
        const int* __restrict__ xx, const int* __restrict__ yy, int K,
        float* __restrict__ out) {
    __shared__ float slds[SRH * SRW];     // 6.4 KB
    __shared__ float dlds[DRH * DRW];     // 10.3 KB
    __shared__ int kox[128], koy[128];
    __shared__ float kd[128];
    __shared__ int recs[KCAP];
    __shared__ float tss[KCAP];
    __shared__ float4 ent[KCAP];
    __shared__ float wt[441];
    __shared__ int nkeep, ne;

    int tid = threadIdx.x;
    int b = blockIdx.z;
    int i0 = blockIdx.y * TS;
    int j0 = blockIdx.x * TS;
    const float* sb = src + b * HWIMG;
    const float* db = dst + b * HWIMG;

    if (tid == 0) { nkeep = 0; ne = 0; }

    // ---- Branch-free bulk staging (all loads independent, issued together)
    for (int t = tid; t < SRH * SRW; t += 256) {          // 7 rounds
        int r = i0 - 12 + t / SRW, c = j0 - 12 + t % SRW;
        int cr = min(max(r, 0), HH - 1), cc = min(max(c, 0), WW - 1);
        float v = sb[cr * WW + cc];                        // unconditional load
        slds[t] = (r >= 0 && r < HH && c >= 0 && c < WW) ? v : 0.f;
    }
    for (int t = tid; t < DRH * DRW; t += 256) {          // 11 rounds
        int r = i0 - 15 + t / DRW, c = j0 - 20 + t % DRW;
        int cr = min(max(r, 0), HH - 1), cc = min(max(c, 0), WW - 1);
        float v = db[cr * WW + cc];
        dlds[t] = (r >= 0 && r < HH && c >= 0 && c < WW) ? v : 0.f;
    }
    for (int t = tid; t < K; t += 256) {
        int ox = xx[t], oy = yy[t];
        kox[t] = ox; koy[t] = oy;
        kd[t] = 20.0f * sqrtf((float)(ox * ox + oy * oy));
    }
    for (int t = tid; t < 441; t += 256) {
        int dy = t / 21 - 10;
        int dx = t % 21 - 10;
        wt[t] = expf(-sqrtf((float)(dx * dx + dy * dy)) / 5.0f);
    }
    __syncthreads();

    // ---- Phase 1: keeper detection over the 36x36 region (LDS) ----
    for (int t = tid; t < 36 * 36; t += 256) {            // 6 rounds
        int rl = t / 36, cl = t % 36;
        int li = rl + 2, lj = cl + 2;     // slds coords (origin i0-12, j0-12)
        if (slds[li * SRW + lj] > 0.5f) { // OOB staged as 0
            // smaller-lin-index nbrs: rows -2,-1 (dj -2..2), row 0 (dj -2,-1)
            float m = 0.f;
#pragma unroll
            for (int p = 0; p < 12; ++p) {
                int di = (p < 5) ? -2 : (p < 10 ? -1 : 0);
                int dj = (p < 5) ? (p - 2) : (p < 10 ? (p - 7) : (p - 12));
                m = fmaxf(m, slds[(li + di) * SRW + (lj + dj)]);
            }
            if (m <= 0.5f) {
                int gi = i0 - 10 + rl, gj = j0 - 10 + cl;
                bool inner = (gi >= 2) && (gi < HH - 2) && (gj >= 2) && (gj < WW - 2);
                float ts = inner ? theta_lds(slds, SRW, li, lj)
                                 : theta_at(sb, gi, gj);
                int pos = atomicAdd(&nkeep, 1);           // LDS atomic
                if (pos < KCAP) { recs[pos] = gj | (gi << 10); tss[pos] = ts; }
            }
        }
    }
    __syncthreads();

    // ---- Phase 2: wave-per-keeper 105-offset search (lex (score,k) argmin)
    int nk = (nkeep < KCAP) ? nkeep : KCAP;
    int lane = tid & 63;
    int wv = tid >> 6;
    for (int w = wv; w < nk; w += 4) {
        int rec = recs[w];
        int kj = rec & 1023;
        int ki = rec >> 10;
        float ts = tss[w];
        int kli = ki - i0 + 15;           // dlds coords (origin i0-15, j0-20)
        int klj = kj - j0 + 20;

        float best = 1e9f;
        int bk = 1 << 20;
#pragma unroll
        for (int rr = 0; rr < 2; ++rr) {
            int k = lane + rr * 64;
            if (k < K) {
                int pli = kli + koy[k], plj = klj + kox[k];
                if (dlds[pli * DRW + plj] > 0.5f) {       // OOB staged as 0
                    int pi = ki + koy[k], pj = kj + kox[k];
                    bool inner = (pi >= 2) && (pi < HH - 2) && (pj >= 2) && (pj < WW - 2);
                    float td = inner ? theta_lds(dlds, DRW, pli, plj)
                                     : theta_at(db, pi, pj);
                    float sc = kd[k] + 10.5f * (1.0f - cosf(ts - td));
                    if (sc < best || (sc == best && k < bk)) { best = sc; bk = k; }
                }
            }
        }
#pragma unroll
        for (int off = 32; off >= 1; off >>= 1) {
            float ob = __shfl_down(best, off, 64);
            int ok = __shfl_down(bk, off, 64);
            if (ob < best || (ob == best && ok < bk)) { best = ob; bk = ok; }
        }
        if (lane == 0 && best < 5e8f) {
            int pos = atomicAdd(&ne, 1);                  // LDS atomic
            if (pos < KCAP)
                ent[pos] = make_float4((float)kj, (float)ki,
                                       (float)kox[bk], (float)koy[bk]);
        }
    }
    __syncthreads();

    // ---- Phase 3: 21x21 weighted diffusion, 1 px/thread ----
    int nn = (ne < KCAP) ? ne : KCAP;
    int gj = j0 + (tid & 15);
    int gi = i0 + (tid >> 4);
    float nx = 0.f, ny = 0.f, de = 0.f;
    for (int c = 0; c < nn; ++c) {
        float4 E = ent[c];                                // broadcast LDS read
        int dj = (int)E.x - gj;
        int di = (int)E.y - gi;
        if (dj >= -10 && dj <= 10 && di >= -10 && di <= 10) {
            float w = wt[(di + 10) * 21 + dj + 10];
            de += w; nx += w * E.z; ny += w * E.w;
        }
    }
    float inv = 0.6f / (de + 1e-6f);
    int obase = b * 2 * HWIMG;
    out[obase + gi * WW + gj] = (float)gj + nx * inv;
    out[obase + HWIMG + gi * WW + gj] = (float)gi + ny * inv;
}

// ---------------------------------------------------------------------------
extern "C" void kernel_launch(void* const* d_in, const int* in_sizes, int n_in,
                              void* d_out, int out_size, void* d_ws, size_t ws_size,
                              hipStream_t stream) {
    const float* src = (const float*)d_in[0];
    const float* dst = (const float*)d_in[1];
    const int* xx = (const int*)d_in[2];
    const int* yy = (const int*)d_in[3];
    int K = in_sizes[2];  // 105

    float* out = (float*)d_out;
    dim3 grid(TXN, TYN, BB);
    fused_kernel<<<grid, dim3(256), 0, stream>>>(src, dst, xx, yy, K, out);
}

// Round 4
// 91.678 us; speedup vs baseline: 1.1872x; 1.1872x over previous
//
#include <hip/hip_runtime.h>
#include <math.h>

#define BB 2
#define HH 256
#define WW 832
#define HWIMG (HH * WW)

#define TS 16              // output tile 16x16, 1 px/thread, 256 thr/block
#define TXN (WW / TS)      // 52
#define TYN (HH / TS)      // 16

#define KCAP 160           // keepers in 36x36 pairwise Chebyshev>=3 -> max 144
#define ECAP 128           // edge-pixel list (expect ~26, 2% of 1296)
#define HCAP 192           // hit list (expect ~26)

// Staged LDS regions, rows padded to 64 cols (pow2 -> zero idiv, no conflicts)
//   src: rows [i0-12, i0+27] (40), meaningful cols [j0-12, j0+27]
//   dst: rows [i0-15, i0+30] (46), meaningful cols [j0-19, j0+34]
#define SRH 40
#define SRW 64
#define DRH 46
#define DRW 64

// ---------------------------------------------------------------------------
// Orientation at (i,j), GLOBAL memory, full wrap (jnp.roll) + one-sided
// border gradients. Used only for image-border pixels (rare).
// ---------------------------------------------------------------------------
__device__ inline float theta_at(const float* __restrict__ m, int i, int j) {
    int ri[5], cj[5];
#pragma unroll
    for (int t = 0; t < 5; ++t) {
        int r = i + t - 2; r = (r < 0) ? r + HH : (r >= HH ? r - HH : r);
        int c = j + t - 2; c = (c < 0) ? c + WW : (c >= WW ? c - WW : c);
        ri[t] = r * WW; cj[t] = c;
    }
    float S[5][5];
#pragma unroll
    for (int a = 0; a < 5; ++a)
#pragma unroll
        for (int c = 0; c < 5; ++c)
            S[a][c] = m[ri[a] + cj[c]];
    float ct[5], cm[5], cb[5];
#pragma unroll
    for (int c = 0; c < 5; ++c) {
        ct[c] = S[0][c] + S[1][c] + S[2][c];
        cm[c] = S[1][c] + S[2][c] + S[3][c];
        cb[c] = S[2][c] + S[3][c] + S[4][c];
    }
    float Bm = ct[1] + ct[2] + ct[3];
    float Bp = cb[1] + cb[2] + cb[3];
    float Bl = cm[0] + cm[1] + cm[2];
    float Br = cm[2] + cm[3] + cm[4];
    float Bc = cm[1] + cm[2] + cm[3];
    float gy = (i == 0) ? (Bp - Bc) : (i == HH - 1) ? (Bc - Bm) : 0.5f * (Bp - Bm);
    float gx = (j == 0) ? (Br - Bc) : (j == WW - 1) ? (Bc - Bl) : 0.5f * (Br - Bl);
    return atan2f(gy, gx);
}

// ---------------------------------------------------------------------------
// Orientation from a STAGED LDS region, interior pixels only (>=2 px from the
// image border): no wrap triggers, gradients purely central, staged values
// are exact copies -> bit-identical to theta_at.
// ---------------------------------------------------------------------------
__device__ inline float theta_lds(const float* __restrict__ m, int stride,
                                  int li, int lj) {
    const float* p = m + (li - 2) * stride + (lj - 2);
    float S[5][5];
#pragma unroll
    for (int a = 0; a < 5; ++a)
#pragma unroll
        for (int c = 0; c < 5; ++c)
            S[a][c] = p[a * stride + c];
    float ct[5], cm[5], cb[5];
#pragma unroll
    for (int c = 0; c < 5; ++c) {
        ct[c] = S[0][c] + S[1][c] + S[2][c];
        cm[c] = S[1][c] + S[2][c] + S[3][c];
        cb[c] = S[2][c] + S[3][c] + S[4][c];
    }
    float Bm = ct[1] + ct[2] + ct[3];
    float Bp = cb[1] + cb[2] + cb[3];
    float Bl = cm[0] + cm[1] + cm[2];
    float Br = cm[2] + cm[3] + cm[4];
    float gy = 0.5f * (Bp - Bm);
    float gx = 0.5f * (Br - Bl);
    return atan2f(gy, gx);
}

// ---------------------------------------------------------------------------
// Fused kernel, compaction-structured:
//   stage (row-per-wave, loop-invariant col clamp, pow2 stride, unrolled)
//   -> edge scan (mask only, append) -> keeper+theta_s (1 thread/edge)
//   -> hit scan (mask only, append)  -> score (1 thread/hit, 64b atomicMin
//      lex (score,k))                -> per-keeper entry table -> diffusion.
// All expensive bodies run with every lane doing real work.
// ---------------------------------------------------------------------------
__global__ __launch_bounds__(256) void fused_kernel(
        const float* __restrict__ src, const float* __restrict__ dst,
        const int* __restrict__ xx, const int* __restrict__ yy, int K,
        float* __restrict__ out) {
    __shared__ float slds[SRH * SRW];            // 10.0 KB
    __shared__ float dlds[DRH * DRW];            // 11.5 KB
    __shared__ int kox[112], koy[112];
    __shared__ float kd[112];
    __shared__ float wt[441];
    __shared__ int elist[ECAP];
    __shared__ int recs[KCAP];
    __shared__ float tss[KCAP];
    __shared__ unsigned long long best64[KCAP];
    __shared__ int hits[HCAP];
    __shared__ float4 ent[KCAP];
    __shared__ int nedge, nkeep, nhit;

    int tid = threadIdx.x;
    int lane = tid & 63;
    int wv = tid >> 6;
    int b = blockIdx.z;
    int i0 = blockIdx.y * TS;
    int j0 = blockIdx.x * TS;
    const float* sb = src + b * HWIMG;
    const float* db = dst + b * HWIMG;

    if (tid == 0) { nedge = 0; nkeep = 0; nhit = 0; }
    for (int t = tid; t < KCAP; t += 256) best64[t] = ~0ULL;

    // ---- Staging: row-per-wave; col/clamp/validity loop-invariant per lane;
    //      fully unrolled so all loads are issued together (one HBM latency).
    {
        int c = j0 - 12 + lane;
        int cc = min(max(c, 0), WW - 1);
        bool cok = (c >= 0) && (c < WW);
#pragma unroll
        for (int rr = 0; rr < 10; ++rr) {        // 40 rows, 4 waves
            int row = wv + 4 * rr;
            int r = i0 - 12 + row;
            int cr = min(max(r, 0), HH - 1);
            float v = sb[cr * WW + cc];
            slds[row * SRW + lane] = (cok && r >= 0 && r < HH) ? v : 0.f;
        }
    }
    {
        int c = j0 - 20 + lane;
        int cc = min(max(c, 0), WW - 1);
        bool cok = (c >= 0) && (c < WW);
#pragma unroll
        for (int rr = 0; rr < 12; ++rr) {        // 46 rows, 4 waves
            int row = wv + 4 * rr;
            if (row < DRH) {
                int r = i0 - 15 + row;
                int cr = min(max(r, 0), HH - 1);
                float v = db[cr * WW + cc];
                dlds[row * DRW + lane] = (cok && r >= 0 && r < HH) ? v : 0.f;
            }
        }
    }
    for (int t = tid; t < K; t += 256) {
        int ox = xx[t], oy = yy[t];
        kox[t] = ox; koy[t] = oy;
        kd[t] = 20.0f * sqrtf((float)(ox * ox + oy * oy));
    }
    for (int t = tid; t < 21 * 32; t += 256) {   // 441 wt entries, pow2 decode
        int dy = t >> 5, dx = t & 31;
        if (dx < 21)
            wt[dy * 21 + dx] = expf(-sqrtf((float)((dx - 10) * (dx - 10) +
                                                   (dy - 10) * (dy - 10))) / 5.0f);
    }
    __syncthreads();

    // ---- Edge scan over 36x36 keeper region (mask test only) ----
    for (int t = tid; t < 36 * 64; t += 256) {
        int cl = t & 63, rl = t >> 6;
        if (cl < 36 && slds[(rl + 2) * SRW + (cl + 2)] > 0.5f) {
            int p = atomicAdd(&nedge, 1);        // LDS atomic
            if (p < ECAP) elist[p] = (rl << 8) | cl;
        }
    }
    __syncthreads();

    // ---- Keeper check + theta_s: one thread per edge pixel ----
    int nE = (nedge < ECAP) ? nedge : ECAP;
    for (int t = tid; t < nE; t += 256) {
        int rl = elist[t] >> 8, cl = elist[t] & 255;
        int li = rl + 2, lj = cl + 2;
        // smaller-lin-index nbrs: rows -2,-1 (dj -2..2), row 0 (dj -2,-1)
        float m = 0.f;
#pragma unroll
        for (int p = 0; p < 12; ++p) {
            int di = (p < 5) ? -2 : (p < 10 ? -1 : 0);
            int dj = (p < 5) ? (p - 2) : (p < 10 ? (p - 7) : (p - 12));
            m = fmaxf(m, slds[(li + di) * SRW + (lj + dj)]);
        }
        if (m <= 0.5f) {
            int gi = i0 - 10 + rl, gj = j0 - 10 + cl;
            bool inner = (gi >= 2) && (gi < HH - 2) && (gj >= 2) && (gj < WW - 2);
            float ts = inner ? theta_lds(slds, SRW, li, lj)
                             : theta_at(sb, gi, gj);
            int p = atomicAdd(&nkeep, 1);        // LDS atomic
            if (p < KCAP) { recs[p] = gj | (gi << 10); tss[p] = ts; }
        }
    }
    __syncthreads();

    // ---- Hit scan: one item per (keeper, offset); mask test only ----
    int nk = (nkeep < KCAP) ? nkeep : KCAP;
    for (int t = tid; t < nk * 128; t += 256) {
        int w = t >> 7, k = t & 127;
        if (k < K) {
            int rec = recs[w];
            int kj = rec & 1023, ki = rec >> 10;
            int pli = ki - i0 + 15 + koy[k];
            int plj = kj - j0 + 20 + kox[k];
            if (dlds[pli * DRW + plj] > 0.5f) {  // OOB staged as 0
                int p = atomicAdd(&nhit, 1);     // LDS atomic
                if (p < HCAP) hits[p] = (w << 7) | k;
            }
        }
    }
    __syncthreads();

    // ---- Score: one thread per hit; lex (score,k) argmin via 64b atomicMin.
    //      Scores are non-negative -> float bits are order-monotone; equal
    //      score bits -> smaller k wins = argmin-first semantics.
    int nh = (nhit < HCAP) ? nhit : HCAP;
    for (int t = tid; t < nh; t += 256) {
        int w = hits[t] >> 7, k = hits[t] & 127;
        int rec = recs[w];
        int kj = rec & 1023, ki = rec >> 10;
        int pi = ki + koy[k], pj = kj + kox[k];
        bool inner = (pi >= 2) && (pi < HH - 2) && (pj >= 2) && (pj < WW - 2);
        float td = inner ? theta_lds(dlds, DRW, pi - i0 + 15, pj - j0 + 20)
                         : theta_at(db, pi, pj);
        float sc = kd[k] + 10.5f * (1.0f - cosf(tss[w] - td));
        unsigned long long pk =
            ((unsigned long long)__float_as_uint(sc) << 32) | (unsigned)k;
        atomicMin(&best64[w], pk);
    }
    __syncthreads();

    // ---- Per-keeper entry table (deterministic order; invalid -> sentinel
    //      that auto-fails the +-10 range test) ----
    for (int t = tid; t < nk; t += 256) {
        unsigned long long v = best64[t];
        if (v != ~0ULL) {
            int k = (int)(v & 0xffffffffULL);
            int rec = recs[t];
            ent[t] = make_float4((float)(rec & 1023), (float)(rec >> 10),
                                 (float)kox[k], (float)koy[k]);
        } else {
            ent[t] = make_float4(-1e4f, -1e4f, 0.f, 0.f);
        }
    }
    __syncthreads();

    // ---- Diffusion: 1 px/thread over per-keeper entries ----
    int gj = j0 + (tid & 15);
    int gi = i0 + (tid >> 4);
    float nx = 0.f, ny = 0.f, de = 0.f;
    for (int w = 0; w < nk; ++w) {
        float4 E = ent[w];                       // broadcast LDS read
        int dj = (int)E.x - gj;
        int di = (int)E.y - gi;
        if (dj >= -10 && dj <= 10 && di >= -10 && di <= 10) {
            float w_ = wt[(di + 10) * 21 + dj + 10];
            de += w_; nx += w_ * E.z; ny += w_ * E.w;
        }
    }
    float inv = 0.6f / (de + 1e-6f);
    int obase = b * 2 * HWIMG;
    out[obase + gi * WW + gj] = (float)gj + nx * inv;
    out[obase + HWIMG + gi * WW + gj] = (float)gi + ny * inv;
}

// ---------------------------------------------------------------------------
extern "C" void kernel_launch(void* const* d_in, const int* in_sizes, int n_in,
                              void* d_out, int out_size, void* d_ws, size_t ws_size,
                              hipStream_t stream) {
    const float* src = (const float*)d_in[0];
    const float* dst = (const float*)d_in[1];
    const int* xx = (const int*)d_in[2];
    const int* yy = (const int*)d_in[3];
    int K = in_sizes[2];  // 105

    float* out = (float*)d_out;
    dim3 grid(TXN, TYN, BB);
    fused_kernel<<<grid, dim3(256), 0, stream>>>(src, dst, xx, yy, K, out);
}